// Round 1
// baseline (456.355 us; speedup 1.0000x reference)
//
#include <hip/hip_runtime.h>

// Problem constants (fixed by reference): B=128, L=256, F=P=4, IN=1024, H=256, C=7
#define NN 32768        // N = B*L
#define INF 1024
#define HF 256

typedef __bf16 bf16x8 __attribute__((ext_vector_type(8)));
typedef float f32x4 __attribute__((ext_vector_type(4)));

__device__ __forceinline__ float bf2f(unsigned short u) {
  union { unsigned int i; float f; } v; v.i = ((unsigned int)u) << 16; return v.f;
}
__device__ __forceinline__ unsigned short f2bf(float f) {
  union { float f; unsigned int i; } v; v.f = f;
  unsigned int x = v.i;
  return (unsigned short)((x + 0x7fffu + ((x >> 16) & 1u)) >> 16);  // RNE
}

// async global->LDS, 16B per lane; dest = lds base (wave-uniform) + lane*16
__device__ __forceinline__ void ld_lds16(const unsigned short* g, unsigned short* l) {
  __builtin_amdgcn_global_load_lds(
      (__attribute__((address_space(1))) const unsigned int*)g,
      (__attribute__((address_space(3))) unsigned int*)l, 16, 0, 0);
}

// ---- weight repack: WbigT[n][k] (1024x1024 bf16) = [W0|W1|Wroot|Wskip]^T,
//      WsmT[n][k] (256x512 bf16)  = [Wgrt;Wrel]^T
__global__ void diagcn_convw(const float* __restrict__ Wrgcn, const float* __restrict__ Wroot,
                             const float* __restrict__ Wskip, const float* __restrict__ Wgrt,
                             const float* __restrict__ Wrel,
                             unsigned short* __restrict__ WbigT, unsigned short* __restrict__ WsmT) {
  int idx = blockIdx.x * 256 + threadIdx.x;
  if (idx < 1024 * 1024) {
    int n = idx >> 10, k = idx & 1023;
    float v;
    if (n < 256)      v = Wrgcn[k * 256 + n];
    else if (n < 512) v = Wrgcn[262144 + k * 256 + (n - 256)];
    else if (n < 768) v = Wroot[k * 256 + (n - 512)];
    else              v = Wskip[k * 256 + (n - 768)];
    WbigT[idx] = f2bf(v);
  } else {
    int i2 = idx - 1024 * 1024;             // < 131072
    int n = i2 >> 9, k = i2 & 511;
    float v = (k < 256) ? Wgrt[k * 256 + n] : Wrel[(k - 256) * 256 + n];
    WsmT[i2] = f2bf(v);
  }
}

// ---- x fp32 -> bf16
__global__ void diagcn_convx(const float* __restrict__ x, unsigned short* __restrict__ Xbf) {
  int idx = blockIdx.x * 256 + threadIdx.x;  // < N*IN/4
  float4 v = ((const float4*)x)[idx];
  ushort4 u; u.x = f2bf(v.x); u.y = f2bf(v.y); u.z = f2bf(v.z); u.w = f2bf(v.w);
  ((ushort4*)Xbf)[idx] = u;
}

// ---- bf16 GEMM: C[M x Nt] = A[M x K] * BT[Nt x K]^T, 128x128 tile, BK=64.
// EPI=0: store bf16 to Y (ldc=1024). EPI=1: z = acc + brel + bskip + Yskip, fp32 (ldc=256).
template <int EPI>
__global__ __launch_bounds__(256)
void diagcn_gemm(const unsigned short* __restrict__ A, const unsigned short* __restrict__ BT,
                 void* __restrict__ Cout, const unsigned short* __restrict__ Yfull,
                 const float* __restrict__ brel, const float* __restrict__ bskip, int K) {
  __shared__ unsigned short As[128 * 64];
  __shared__ unsigned short Bs[128 * 64];
  const int tid = threadIdx.x;
  const int w = tid >> 6, lane = tid & 63;
  const int wm = w >> 1, wn = w & 1;
  const int quad = lane >> 4, l15 = lane & 15;
  const int m0 = blockIdx.y << 7;
  const int n0 = blockIdx.x << 7;
  const int rowg = lane >> 3;                 // 0..7 within 8-row group
  const int kbsw = (lane & 7) ^ rowg;         // XOR-swizzled source k-block

  f32x4 acc[4][4] = {};

  const unsigned short* Abase = A + (size_t)m0 * K + kbsw * 8;
  const unsigned short* Bbase = BT + (size_t)n0 * K + kbsw * 8;

  for (int k0 = 0; k0 < K; k0 += 64) {
#pragma unroll
    for (int t = 0; t < 4; ++t) {
      int grp = w * 4 + t;                    // 16 groups of 8 rows
      int rl = grp * 8 + rowg;
      ld_lds16(Abase + (size_t)rl * K + k0, &As[grp * 512]);
      ld_lds16(Bbase + (size_t)rl * K + k0, &Bs[grp * 512]);
    }
    __syncthreads();
#pragma unroll
    for (int ks = 0; ks < 2; ++ks) {
      bf16x8 av[4], bv[4];
      int kb = ks * 4 + quad;
#pragma unroll
      for (int i = 0; i < 4; ++i) {
        int ra = wm * 64 + i * 16 + l15;
        int rb = wn * 64 + i * 16 + l15;
        av[i] = *(const bf16x8*)&As[ra * 64 + ((kb ^ (ra & 7)) << 3)];
        bv[i] = *(const bf16x8*)&Bs[rb * 64 + ((kb ^ (rb & 7)) << 3)];
      }
#pragma unroll
      for (int i = 0; i < 4; ++i)
#pragma unroll
        for (int j = 0; j < 4; ++j)
          acc[i][j] = __builtin_amdgcn_mfma_f32_16x16x32_bf16(av[i], bv[j], acc[i][j], 0, 0, 0);
    }
    __syncthreads();
  }

  if (EPI == 0) {
    unsigned short* Y = (unsigned short*)Cout;
#pragma unroll
    for (int i = 0; i < 4; ++i)
#pragma unroll
      for (int j = 0; j < 4; ++j) {
        int row = m0 + wm * 64 + i * 16 + quad * 4;
        int col = n0 + wn * 64 + j * 16 + l15;
#pragma unroll
        for (int r = 0; r < 4; ++r)
          Y[(size_t)(row + r) * 1024 + col] = f2bf(acc[i][j][r]);
      }
  } else {
    float* Z = (float*)Cout;
#pragma unroll
    for (int i = 0; i < 4; ++i)
#pragma unroll
      for (int j = 0; j < 4; ++j) {
        int row = m0 + wm * 64 + i * 16 + quad * 4;
        int col = n0 + wn * 64 + j * 16 + l15;
#pragma unroll
        for (int r = 0; r < 4; ++r) {
          float v = acc[i][j][r] + brel[col] + bskip[col] +
                    bf2f(Yfull[(size_t)(row + r) * 1024 + 768 + col]);
          Z[(size_t)(row + r) * 256 + col] = v;
        }
      }
  }
}

// ---- RGCN aggregate: h_i = Yroot_i + b + sum_r mean_{j in win, rel=r} Y_r[j]
// one wave per node, 4 channels per lane. Y cols: [Y0|Y1|Yroot|Yskip]
__global__ __launch_bounds__(256)
void diagcn_h(const unsigned short* __restrict__ Y, const int* __restrict__ spk,
              const float* __restrict__ brgcn, float* __restrict__ h,
              unsigned short* __restrict__ A2) {
  int gid = blockIdx.x * 256 + threadIdx.x;
  int node = gid >> 6;
  int c0 = (gid & 63) << 2;
  int p = node & 255;
  int base = node - p;
  int lo = p - 4; if (lo < 0) lo = 0;
  int hi = p + 4; if (hi > 255) hi = 255;
  int si = spk[node];
  float a0x = 0, a0y = 0, a0z = 0, a0w = 0;
  float a1x = 0, a1y = 0, a1z = 0, a1w = 0;
  int n0 = 0, n1 = 0;
  for (int j = lo; j <= hi; ++j) {
    int nj = base + j;
    int sj = spk[nj];
    if (si & sj) {  // rel 1
      ushort4 v = *(const ushort4*)&Y[(size_t)nj * 1024 + 256 + c0];
      a1x += bf2f(v.x); a1y += bf2f(v.y); a1z += bf2f(v.z); a1w += bf2f(v.w);
      n1++;
    } else {        // rel 0
      ushort4 v = *(const ushort4*)&Y[(size_t)nj * 1024 + c0];
      a0x += bf2f(v.x); a0y += bf2f(v.y); a0z += bf2f(v.z); a0w += bf2f(v.w);
      n0++;
    }
  }
  ushort4 vr = *(const ushort4*)&Y[(size_t)node * 1024 + 512 + c0];
  float4 b = *(const float4*)&brgcn[c0];
  float i0 = 1.0f / (float)(n0 > 1 ? n0 : 1);
  float i1 = 1.0f / (float)(n1 > 1 ? n1 : 1);
  float hx = bf2f(vr.x) + b.x + a0x * i0 + a1x * i1;
  float hy = bf2f(vr.y) + b.y + a0y * i0 + a1y * i1;
  float hz = bf2f(vr.z) + b.z + a0z * i0 + a1z * i1;
  float hw = bf2f(vr.w) + b.w + a0w * i0 + a1w * i1;
  float4 hv; hv.x = hx; hv.y = hy; hv.z = hz; hv.w = hw;
  *(float4*)&h[(size_t)node * 256 + c0] = hv;
  ushort4 u; u.x = f2bf(hx); u.y = f2bf(hy); u.z = f2bf(hz); u.w = f2bf(hw);
  *(ushort4*)&A2[(size_t)node * 512 + c0] = u;
}

// ---- GraphConv neighbor sum (aggr=add over window incl. self)
__global__ __launch_bounds__(256)
void diagcn_neigh(const float* __restrict__ h, unsigned short* __restrict__ A2) {
  int gid = blockIdx.x * 256 + threadIdx.x;
  int node = gid >> 6;
  int c0 = (gid & 63) << 2;
  int p = node & 255;
  int base = node - p;
  int lo = p - 4; if (lo < 0) lo = 0;
  int hi = p + 4; if (hi > 255) hi = 255;
  float sx = 0, sy = 0, sz = 0, sw = 0;
  for (int j = lo; j <= hi; ++j) {
    float4 v = *(const float4*)&h[(size_t)(base + j) * 256 + c0];
    sx += v.x; sy += v.y; sz += v.z; sw += v.w;
  }
  ushort4 u; u.x = f2bf(sx); u.y = f2bf(sy); u.z = f2bf(sz); u.w = f2bf(sw);
  *(ushort4*)&A2[(size_t)node * 512 + 256 + c0] = u;
}

// ---- classifier + per-node loss: one wave per node
__global__ __launch_bounds__(256)
void diagcn_out(const float* __restrict__ z, const float* __restrict__ Wcls,
                const float* __restrict__ bcls, const int* __restrict__ labels,
                float* __restrict__ out, float* __restrict__ lossp) {
  __shared__ float Wc[256 * 7 + 7];
  for (int i = threadIdx.x; i < 256 * 7 + 7; i += 256)
    Wc[i] = (i < 1792) ? Wcls[i] : bcls[i - 1792];
  __syncthreads();
  int node = blockIdx.x * 4 + (threadIdx.x >> 6);
  int lane = threadIdx.x & 63;
  int c0 = lane << 2;
  float4 zv = *(const float4*)&z[(size_t)node * 256 + c0];
  float zz[4] = {zv.x, zv.y, zv.z, zv.w};
  float pr[7] = {0, 0, 0, 0, 0, 0, 0};
#pragma unroll
  for (int cc = 0; cc < 4; ++cc) {
    const float* wr = &Wc[(c0 + cc) * 7];
#pragma unroll
    for (int k = 0; k < 7; ++k) pr[k] += zz[cc] * wr[k];
  }
#pragma unroll
  for (int o = 32; o > 0; o >>= 1)
#pragma unroll
    for (int k = 0; k < 7; ++k) pr[k] += __shfl_down(pr[k], o, 64);
  if (lane == 0) {
    float o7[7], m = -1e30f;
#pragma unroll
    for (int k = 0; k < 7; ++k) {
      o7[k] = pr[k] + Wc[1792 + k];
      out[(size_t)node * 7 + k] = o7[k];
      m = fmaxf(m, o7[k]);
    }
    float s = 0;
#pragma unroll
    for (int k = 0; k < 7; ++k) s += expf(o7[k] - m);
    int lab = labels[node];
    lossp[node] = m + logf(s) - o7[lab];
  }
}

__global__ void diagcn_lred(const float* __restrict__ lp, float* __restrict__ dst) {
  __shared__ float sm[256];
  float s = 0;
  for (int i = threadIdx.x; i < NN; i += 256) s += lp[i];
  sm[threadIdx.x] = s;
  __syncthreads();
  for (int o = 128; o > 0; o >>= 1) {
    if (threadIdx.x < o) sm[threadIdx.x] += sm[threadIdx.x + o];
    __syncthreads();
  }
  if (threadIdx.x == 0) dst[0] = sm[0] * (1.0f / (float)NN);
}

extern "C" void kernel_launch(void* const* d_in, const int* in_sizes, int n_in,
                              void* d_out, int out_size, void* d_ws, size_t ws_size,
                              hipStream_t stream) {
  const float* x      = (const float*)d_in[0];
  const int* speakers = (const int*)d_in[2];
  const int* labels   = (const int*)d_in[3];
  const float* Wrgcn  = (const float*)d_in[6];
  const float* Wroot  = (const float*)d_in[7];
  const float* brgcn  = (const float*)d_in[8];
  const float* Wrel   = (const float*)d_in[9];
  const float* brel   = (const float*)d_in[10];
  const float* Wgrt   = (const float*)d_in[11];
  const float* Wskip  = (const float*)d_in[12];
  const float* bskip  = (const float*)d_in[13];
  const float* Wcls   = (const float*)d_in[14];
  const float* bcls   = (const float*)d_in[15];
  float* out = (float*)d_out;

  // workspace layout (bytes)
  const size_t OFF_XBF  = 0;                  // 67,108,864  (bf16 X; later reused for z+lossp)
  const size_t OFF_WBIG = 67108864;           //  2,097,152
  const size_t OFF_WSM  = 69206016;           //    262,144
  const size_t OFF_Y    = 69468160;           // 67,108,864  (bf16 [Y0|Y1|Yroot|Yskip])
  const size_t OFF_H    = 136577024;          // 33,554,432  (fp32 h)
  const size_t OFF_A2   = 170131456;          // 33,554,432  (bf16 [h|neigh])
  const size_t NEED     = 203685888;
  if (ws_size < NEED) return;  // insufficient scratch — would need a redesign

  char* ws = (char*)d_ws;
  unsigned short* Xbf   = (unsigned short*)(ws + OFF_XBF);
  unsigned short* WbigT = (unsigned short*)(ws + OFF_WBIG);
  unsigned short* WsmT  = (unsigned short*)(ws + OFF_WSM);
  unsigned short* Y     = (unsigned short*)(ws + OFF_Y);
  float* h              = (float*)(ws + OFF_H);
  unsigned short* A2    = (unsigned short*)(ws + OFF_A2);
  float* z              = (float*)(ws + OFF_XBF);               // reuse (Xbf dead after GEMM1)
  float* lossp          = (float*)(ws + OFF_XBF + 33554432);

  diagcn_convw<<<dim3(4608), dim3(256), 0, stream>>>(Wrgcn, Wroot, Wskip, Wgrt, Wrel, WbigT, WsmT);
  diagcn_convx<<<dim3(NN * INF / 4 / 256), dim3(256), 0, stream>>>(x, Xbf);
  // GEMM1: Y[32768 x 1024] = Xbf @ WbigT^T ; grid.x = n-tiles(8), grid.y = m-tiles(256)
  diagcn_gemm<0><<<dim3(8, 256), dim3(256), 0, stream>>>(Xbf, WbigT, (void*)Y, nullptr, nullptr, nullptr, 1024);
  diagcn_h<<<dim3(NN / 4), dim3(256), 0, stream>>>(Y, speakers, brgcn, h, A2);
  diagcn_neigh<<<dim3(NN / 4), dim3(256), 0, stream>>>(h, A2);
  // GEMM2: z[32768 x 256] = A2 @ WsmT^T + brel + bskip + Yskip
  diagcn_gemm<1><<<dim3(2, 256), dim3(256), 0, stream>>>(A2, WsmT, (void*)z, Y, brel, bskip, 512);
  diagcn_out<<<dim3(NN / 4), dim3(256), 0, stream>>>(z, Wcls, bcls, labels, out, lossp);
  diagcn_lred<<<dim3(1), dim3(256), 0, stream>>>(lossp, out + (size_t)NN * 7);
}